// Round 19
// baseline (88.945 us; speedup 1.0000x reference)
//
#include <hip/hip_runtime.h>
#include <hip/hip_bf16.h>

#define NB 2
#define NH 16
#define NSQ 2048
#define NSKV 2048
#define ND 64
#define NT (NSKV / 64)
#define LOG2E 1.4426950408889634f
#define BHSTRIDE (NSKV * ND)   // shorts per bh in packed K/V

typedef __attribute__((ext_vector_type(8))) short bf16x8;
typedef __attribute__((ext_vector_type(4))) float f32x4;

__device__ __forceinline__ short f2bf(float x) {   // rne f32->bf16
  union { float f; unsigned u; } c; c.f = x;
  unsigned r = c.u + 0x7fffu + ((c.u >> 16) & 1u);
  return (short)(r >> 16);
}
__device__ __forceinline__ unsigned pack_bf2(float lo, float hi) {
  union { __hip_bfloat162 h; unsigned u; } c;
  c.h = __float22bfloat162_rn(float2{lo, hi});
  return c.u;
}
__device__ __forceinline__ float u2f(unsigned u) {
  union { unsigned u; float f; } c; c.u = u; return c.f;
}
__device__ __forceinline__ float exp2_fast(float x) {
#if __has_builtin(__builtin_amdgcn_exp2f)
  return __builtin_amdgcn_exp2f(x);
#else
  return exp2f(x);
#endif
}

// pi: physical row p (within 64-row tile) holds logical kv:
// kv = b0 + 2b1 + 4*b4 + 8*b2 + 16*b3 + 32*b5 -> QK^T C-reg s[nt][r]
// (lane lq) = score for logical kv r + 4*(nt&1) + 8*lq + 32*(nt>>1),
// so PV A-frags pack fully in-lane.
__device__ __forceinline__ int kvmap(int x) {
  return (x & 3) | (((x >> 4) & 1) << 2) | (((x >> 2) & 1) << 3)
       | (((x >> 3) & 1) << 4) | (x & 32);
}

// ---- fused prepass: one block per (kv-tile, bh) -- verified (R16/R17) ----
__global__ void prep_all(const float* __restrict__ K, const float* __restrict__ V,
                         const float* __restrict__ M, short* __restrict__ Kp,
                         short* __restrict__ Vp, unsigned short* __restrict__ Mt) {
  __shared__ float T[64][65];
  const int tile = blockIdx.x;          // kv tile 0..31
  const int bh   = blockIdx.y;          // 0..31
  const int kv0  = tile * 64;
  const int t    = (int)threadIdx.x;

  // ---- V part (transpose through LDS, then packed B-frag store)
  {
    const float* src = V + ((size_t)bh * NSKV + kv0) * ND;
#pragma unroll
    for (int i = 0; i < 4; ++i) {
      float4 v = *(const float4*)(src + (size_t)((t >> 4) + 16 * i) * ND + (t & 15) * 4);
      T[(t >> 4) + 16 * i][(t & 15) * 4 + 0] = v.x;
      T[(t >> 4) + 16 * i][(t & 15) * 4 + 1] = v.y;
      T[(t >> 4) + 16 * i][(t & 15) * 4 + 2] = v.z;
      T[(t >> 4) + 16 * i][(t & 15) * 4 + 3] = v.w;
    }
    __syncthreads();
    const int d = t >> 2, c = t & 3;
    bf16x8 w0, w1;
#pragma unroll
    for (int j = 0; j < 8; ++j) w0[j] = f2bf(T[c * 16 + j][d]);
#pragma unroll
    for (int j = 0; j < 8; ++j) w1[j] = f2bf(T[c * 16 + 8 + j][d]);
    const int frag  = (d >> 4) * 2 + (c >> 1);
    const int lane0 = (((2 * c) & 3) << 4) | (d & 15);
    const int lane1 = (((2 * c + 1) & 3) << 4) | (d & 15);
    short* dstb = Vp + (size_t)bh * BHSTRIDE + (size_t)tile * 4096 + frag * 512;
    *(bf16x8*)(dstb + lane0 * 8) = w0;
    *(bf16x8*)(dstb + lane1 * 8) = w1;
  }

  // ---- K part (pi-permuted packed A-frag copy)
#pragma unroll
  for (int h = 0; h < 2; ++h) {
    const int u    = t + h * 256;            // 0..511 = frag*64 + lane
    const int nt   = u >> 7, kc = (u >> 6) & 1, lane = u & 63;
    const int prow = nt * 16 + (lane & 15);
    const float* src = K + ((size_t)bh * NSKV + kv0 + kvmap(prow)) * ND
                         + kc * 32 + (lane >> 4) * 8;
    float4 a = *(const float4*)src, b = *(const float4*)(src + 4);
    bf16x8 w;
    w[0]=f2bf(a.x); w[1]=f2bf(a.y); w[2]=f2bf(a.z); w[3]=f2bf(a.w);
    w[4]=f2bf(b.x); w[5]=f2bf(b.y); w[6]=f2bf(b.z); w[7]=f2bf(b.w);
    *(bf16x8*)(Kp + (size_t)bh * BHSTRIDE + (size_t)tile * 4096 + u * 8) = w;
  }

  // ---- mask part: 4 q-tiles (qt = bh*4+i), kt = tile
  {
    const int rl = t >> 4, c = t & 15;
    const int nt   = 2 * (c >> 3) + (c & 1);
    const int lq   = (c >> 1) & 3;
    const int lane = lq * 16 + rl;
#pragma unroll
    for (int i = 0; i < 4; ++i) {
      const int qt  = bh * 4 + i;
      const int row = qt * 16 + rl;
      float4 v = *(const float4*)(M + (size_t)row * NSKV + tile * 64 + c * 4);
      ushort4 o;
      o.x = (unsigned short)f2bf(LOG2E * v.x);
      o.y = (unsigned short)f2bf(LOG2E * v.y);
      o.z = (unsigned short)f2bf(LOG2E * v.z);
      o.w = (unsigned short)f2bf(LOG2E * v.w);
      *(ushort4*)(Mt + (((size_t)qt * 32 + tile) * 64 + lane) * 16 + nt * 4) = o;
    }
  }
}

// ---- main kernel ---------------------------------------------------------
// 1 wave per block (64 thr); wave owns 64 q rows = 4 subtiles of 16.
// No LDS, no barriers: K/V/mask fragments register-streamed from the
// packed workspace, double-buffered one full tile ahead. Halved K/V
// fan-out per q (4-subtile reuse of every fragment byte).
__global__ __launch_bounds__(64, 1)
void attn_fwd(const float* __restrict__ Q, const short* __restrict__ Kp,
              const short* __restrict__ Vp, const unsigned short* __restrict__ Mt,
              const void* __restrict__ scale_p, float* __restrict__ O)
{
  // XCD swizzle: 1024 blocks, 128/XCD; consecutive idx share bh (L2 reuse)
  const int lin = (int)blockIdx.x;
  const int idx = lin >> 3;
  const int bh  = (lin & 7) * 4 + (idx >> 5);  // 4 bh per XCD
  const int qb  = idx & 31;                    // 0..31, 64 q each

  const int ln  = (int)threadIdx.x & 63;
  const int l16 = ln & 15;
  const int lq  = ln >> 4;

  float scale_v;
  {
    union { int i; float f; } u;
    u.i = ((const int*)scale_p)[0];
    float af = fabsf(u.f);
    scale_v = (af >= 1e-6f && af <= 1e6f) ? u.f : (float)u.i;
  }
  const float qmul = LOG2E / scale_v;

  const int q0 = qb * 64;
  const short* Kb = Kp + (size_t)bh * BHSTRIDE;
  const short* Vb = Vp + (size_t)bh * BHSTRIDE;

  // Q as B-frag: qf[qs][kc][j] = Q[q0+qs*16+l16][kc*32+8lq+j]*qmul
  bf16x8 qf[4][2];
#pragma unroll
  for (int qs = 0; qs < 4; ++qs) {
    const float* qrow = Q + ((size_t)bh * NSQ + q0 + qs * 16 + l16) * ND;
#pragma unroll
    for (int kc = 0; kc < 2; ++kc) {
      const float4* p = (const float4*)(qrow + kc * 32 + lq * 8);
      float4 a = p[0], b = p[1];
      bf16x8 f;
      f[0]=f2bf(a.x*qmul); f[1]=f2bf(a.y*qmul); f[2]=f2bf(a.z*qmul); f[3]=f2bf(a.w*qmul);
      f[4]=f2bf(b.x*qmul); f[5]=f2bf(b.y*qmul); f[6]=f2bf(b.z*qmul); f[7]=f2bf(b.w*qmul);
      qf[qs][kc] = f;
    }
  }

  f32x4 oa[4][4];   // oa[qs][dt][r]: O[q=q0+qs*16+lq*4+r][d=dt*16+l16]
  f32x4 lacc[4];
#pragma unroll
  for (int qs = 0; qs < 4; ++qs) {
#pragma unroll
    for (int dt = 0; dt < 4; ++dt) { f32x4 z = {0.f,0.f,0.f,0.f}; oa[qs][dt] = z; }
    f32x4 z = {0.f,0.f,0.f,0.f}; lacc[qs] = z;
  }

  bf16x8 ones;
#pragma unroll
  for (int j = 0; j < 8; ++j) ones[j] = (short)0x3F80;

  // mask strips: qt = qb*4 + qs, per-qt stride 32768 ushorts, per-tile 1024
  const unsigned short* Mq = Mt + (size_t)(qb * 4) * 32768 + (size_t)ln * 16;

  union MU { uint4 q[2]; unsigned u[8]; };

  auto mload = [&](int t, MU (&m)[4]) {
#pragma unroll
    for (int qs = 0; qs < 4; ++qs) {
      const unsigned short* p = Mq + (size_t)qs * 32768 + (size_t)t * 1024;
      m[qs].q[0] = *(const uint4*)p;
      m[qs].q[1] = *(const uint4*)(p + 8);
    }
  };

  auto kvload = [&](int t, bf16x8 (&kf)[4][2], bf16x8 (&vf)[4][2]) {
    const short* kt = Kb + (size_t)t * 4096 + ln * 8;
    const short* vt = Vb + (size_t)t * 4096 + ln * 8;
#pragma unroll
    for (int f = 0; f < 8; ++f) {
      kf[f >> 1][f & 1] = *(const bf16x8*)(kt + f * 512);
      vf[f >> 1][f & 1] = *(const bf16x8*)(vt + f * 512);
    }
  };

  // QK for one subtile: C-init = mask*log2e (unpacked from bf16 regs)
  auto qk = [&](bf16x8 (&kf)[4][2], int qs, const MU& m, f32x4 (&s)[4]) {
#pragma unroll
    for (int nt = 0; nt < 4; ++nt) {
      const unsigned w0 = m.u[nt * 2], w1 = m.u[nt * 2 + 1];
      f32x4 a;
      a[0] = u2f(w0 << 16); a[1] = u2f(w0 & 0xffff0000u);
      a[2] = u2f(w1 << 16); a[3] = u2f(w1 & 0xffff0000u);
      a = __builtin_amdgcn_mfma_f32_16x16x32_bf16(kf[nt][0], qf[qs][0], a, 0, 0, 0);
      a = __builtin_amdgcn_mfma_f32_16x16x32_bf16(kf[nt][1], qf[qs][1], a, 0, 0, 0);
      s[nt] = a;
    }
  };

  auto smpack = [&](f32x4 (&s)[4], bf16x8 (&pa)[2]) {
#pragma unroll
    for (int nt = 0; nt < 4; ++nt) {
      s[nt][0] = exp2_fast(s[nt][0]);
      s[nt][1] = exp2_fast(s[nt][1]);
      s[nt][2] = exp2_fast(s[nt][2]);
      s[nt][3] = exp2_fast(s[nt][3]);
    }
#pragma unroll
    for (int kc = 0; kc < 2; ++kc) {
      union { unsigned u[4]; bf16x8 v; } w;
      w.u[0] = pack_bf2(s[2*kc][0],   s[2*kc][1]);
      w.u[1] = pack_bf2(s[2*kc][2],   s[2*kc][3]);
      w.u[2] = pack_bf2(s[2*kc+1][0], s[2*kc+1][1]);
      w.u[3] = pack_bf2(s[2*kc+1][2], s[2*kc+1][3]);
      pa[kc] = w.v;
    }
  };

  auto pv = [&](bf16x8 (&vf)[4][2], int qs, bf16x8 (&pa)[2]) {
#pragma unroll
    for (int kc = 0; kc < 2; ++kc) {
#pragma unroll
      for (int dt = 0; dt < 4; ++dt)
        oa[qs][dt] = __builtin_amdgcn_mfma_f32_16x16x32_bf16(pa[kc], vf[dt][kc], oa[qs][dt], 0, 0, 0);
      lacc[qs] = __builtin_amdgcn_mfma_f32_16x16x32_bf16(pa[kc], ones, lacc[qs], 0, 0, 0);
    }
  };

  // one KV tile: consume cur set, prefetch next set (full tile of cover)
  auto tile = [&](int t, bf16x8 (&kfc)[4][2], bf16x8 (&vfc)[4][2], MU (&mcc)[4],
                  bf16x8 (&kfn)[4][2], bf16x8 (&vfn)[4][2], MU (&mcn)[4]) {
    if (t + 1 < NT) {
      kvload(t + 1, kfn, vfn);
      mload(t + 1, mcn);
    }
    f32x4 s0[4], s1[4];
    bf16x8 pa0[2], pa1[2];
    // subtile pair (0,1): sm1 fills PV0's MFMA shadow
    qk(kfc, 0, mcc[0], s0);
    qk(kfc, 1, mcc[1], s1);
    smpack(s0, pa0);
    pv(vfc, 0, pa0);
    smpack(s1, pa1);
    pv(vfc, 1, pa1);
    // subtile pair (2,3)
    qk(kfc, 2, mcc[2], s0);
    qk(kfc, 3, mcc[3], s1);
    smpack(s0, pa0);
    pv(vfc, 2, pa0);
    smpack(s1, pa1);
    pv(vfc, 3, pa1);
  };

  bf16x8 kA[4][2], vA[4][2], kB[4][2], vB[4][2];
  MU mA[4], mB[4];
  kvload(0, kA, vA);
  mload(0, mA);

  for (int t = 0; t < NT; t += 2) {
    tile(t,     kA, vA, mA, kB, vB, mB);
    tile(t + 1, kB, vB, mB, kA, vA, mA);
  }

  // ---- epilogue: normalize by lacc (same C-rows as oa), store fp32
#pragma unroll
  for (int qs = 0; qs < 4; ++qs)
#pragma unroll
    for (int r = 0; r < 4; ++r) {
      const float inv = 1.0f / lacc[qs][r];
      float* orow = O + ((size_t)bh * NSQ + q0 + qs * 16 + lq * 4 + r) * ND;
#pragma unroll
      for (int dt = 0; dt < 4; ++dt)
        orow[dt * 16 + l16] = oa[qs][dt][r] * inv;
    }
}

extern "C" void kernel_launch(void* const* d_in, const int* in_sizes, int n_in,
                              void* d_out, int out_size, void* d_ws, size_t ws_size,
                              hipStream_t stream) {
  const float* q     = (const float*)d_in[0];
  const float* k     = (const float*)d_in[1];
  const float* v     = (const float*)d_in[2];
  const float* mask  = (const float*)d_in[3];
  const void*  scale = (const void*)d_in[4];
  float* out = (float*)d_out;

  const size_t NELEM = (size_t)NB * NH * NSKV * ND;   // 4,194,304 shorts each
  short* Kpk = (short*)d_ws;
  short* Vpk = Kpk + NELEM;
  unsigned short* Mtl = (unsigned short*)(Vpk + NELEM);   // 8MB bf16

  prep_all<<<dim3(NSKV / 64, NB * NH), 256, 0, stream>>>(k, v, mask, Kpk, Vpk, Mtl);

  attn_fwd<<<dim3(1024), 64, 0, stream>>>(q, Kpk, Vpk, Mtl, scale, out);
}

// Round 20
// 66.683 us; speedup vs baseline: 1.3339x; 1.3339x over previous
//
#include <hip/hip_runtime.h>
#include <hip/hip_bf16.h>

#define NB 2
#define NH 16
#define NSQ 2048
#define NSKV 2048
#define ND 64
#define NT (NSKV / 64)
#define LOG2E 1.4426950408889634f
#define BHSTRIDE (NSKV * ND)   // shorts per bh in packed K/V

typedef __attribute__((ext_vector_type(8))) short bf16x8;
typedef __attribute__((ext_vector_type(4))) float f32x4;
typedef __attribute__((address_space(1))) const unsigned gas_u32;
typedef __attribute__((address_space(3))) unsigned las_u32;

__device__ __forceinline__ short f2bf(float x) {   // rne f32->bf16
  union { float f; unsigned u; } c; c.f = x;
  unsigned r = c.u + 0x7fffu + ((c.u >> 16) & 1u);
  return (short)(r >> 16);
}
__device__ __forceinline__ unsigned pack_bf2(float lo, float hi) {
  union { __hip_bfloat162 h; unsigned u; } c;
  c.h = __float22bfloat162_rn(float2{lo, hi});
  return c.u;
}
__device__ __forceinline__ float u2f(unsigned u) {
  union { unsigned u; float f; } c; c.u = u; return c.f;
}
__device__ __forceinline__ float exp2_fast(float x) {
#if __has_builtin(__builtin_amdgcn_exp2f)
  return __builtin_amdgcn_exp2f(x);
#else
  return exp2f(x);
#endif
}

// pi: physical row p (within 64-row tile) holds logical kv:
// kv = b0 + 2b1 + 4*b4 + 8*b2 + 16*b3 + 32*b5 -> QK^T C-reg s[nt][r]
// (lane lq) = score for logical kv r + 4*(nt&1) + 8*lq + 32*(nt>>1),
// so PV A-frags pack fully in-lane.
__device__ __forceinline__ int kvmap(int x) {
  return (x & 3) | (((x >> 4) & 1) << 2) | (((x >> 2) & 1) << 3)
       | (((x >> 3) & 1) << 4) | (x & 32);
}

// ---- fused prepass: one block per (kv-tile, bh) --------------------------
__global__ void prep_all(const float* __restrict__ K, const float* __restrict__ V,
                         const float* __restrict__ M, short* __restrict__ Kp,
                         short* __restrict__ Vp, unsigned short* __restrict__ Mt) {
  __shared__ float T[64][65];
  const int tile = blockIdx.x;          // kv tile 0..31
  const int bh   = blockIdx.y;          // 0..31
  const int kv0  = tile * 64;
  const int t    = (int)threadIdx.x;

  // ---- V part (transpose through LDS, then packed B-frag store)
  {
    const float* src = V + ((size_t)bh * NSKV + kv0) * ND;
#pragma unroll
    for (int i = 0; i < 4; ++i) {
      float4 v = *(const float4*)(src + (size_t)((t >> 4) + 16 * i) * ND + (t & 15) * 4);
      T[(t >> 4) + 16 * i][(t & 15) * 4 + 0] = v.x;
      T[(t >> 4) + 16 * i][(t & 15) * 4 + 1] = v.y;
      T[(t >> 4) + 16 * i][(t & 15) * 4 + 2] = v.z;
      T[(t >> 4) + 16 * i][(t & 15) * 4 + 3] = v.w;
    }
    __syncthreads();
    const int d = t >> 2, c = t & 3;
    bf16x8 w0, w1;
#pragma unroll
    for (int j = 0; j < 8; ++j) w0[j] = f2bf(T[c * 16 + j][d]);
#pragma unroll
    for (int j = 0; j < 8; ++j) w1[j] = f2bf(T[c * 16 + 8 + j][d]);
    const int frag  = (d >> 4) * 2 + (c >> 1);
    const int lane0 = (((2 * c) & 3) << 4) | (d & 15);
    const int lane1 = (((2 * c + 1) & 3) << 4) | (d & 15);
    short* dstb = Vp + (size_t)bh * BHSTRIDE + (size_t)tile * 4096 + frag * 512;
    *(bf16x8*)(dstb + lane0 * 8) = w0;
    *(bf16x8*)(dstb + lane1 * 8) = w1;
  }

  // ---- K part (pi-permuted packed A-frag copy)
#pragma unroll
  for (int h = 0; h < 2; ++h) {
    const int u    = t + h * 256;            // 0..511 = frag*64 + lane
    const int nt   = u >> 7, kc = (u >> 6) & 1, lane = u & 63;
    const int prow = nt * 16 + (lane & 15);
    const float* src = K + ((size_t)bh * NSKV + kv0 + kvmap(prow)) * ND
                         + kc * 32 + (lane >> 4) * 8;
    float4 a = *(const float4*)src, b = *(const float4*)(src + 4);
    bf16x8 w;
    w[0]=f2bf(a.x); w[1]=f2bf(a.y); w[2]=f2bf(a.z); w[3]=f2bf(a.w);
    w[4]=f2bf(b.x); w[5]=f2bf(b.y); w[6]=f2bf(b.z); w[7]=f2bf(b.w);
    *(bf16x8*)(Kp + (size_t)bh * BHSTRIDE + (size_t)tile * 4096 + u * 8) = w;
  }

  // ---- mask part: 4 q-tiles (qt = bh*4+i), kt = tile
  {
    const int rl = t >> 4, c = t & 15;
    const int nt   = 2 * (c >> 3) + (c & 1);
    const int lq   = (c >> 1) & 3;
    const int lane = lq * 16 + rl;
#pragma unroll
    for (int i = 0; i < 4; ++i) {
      const int qt  = bh * 4 + i;
      const int row = qt * 16 + rl;
      float4 v = *(const float4*)(M + (size_t)row * NSKV + tile * 64 + c * 4);
      ushort4 o;
      o.x = (unsigned short)f2bf(LOG2E * v.x);
      o.y = (unsigned short)f2bf(LOG2E * v.y);
      o.z = (unsigned short)f2bf(LOG2E * v.z);
      o.w = (unsigned short)f2bf(LOG2E * v.w);
      *(ushort4*)(Mt + (((size_t)qt * 32 + tile) * 64 + lane) * 16 + nt * 4) = o;
    }
  }
}

// ---- main kernel ---------------------------------------------------------
// Best verified structure (R17): 4 waves x 2 subtiles x 16 q = 128 q/block.
// Packed-fragment LDS staging via global_load_lds, double-buffered, ONE
// barrier/tile. bf16 mask as QK^T C-initializer. Dual-pipe interleave:
// QK0 -> QK1 -> vf reads -> sm0 -> [PV0 (MFMA) || sm1 (VALU)] -> PV1.
__global__ __launch_bounds__(256, 2)
void attn_fwd(const float* __restrict__ Q, const short* __restrict__ Kp,
              const short* __restrict__ Vp, const unsigned short* __restrict__ Mt,
              const void* __restrict__ scale_p, float* __restrict__ O)
{
  // bijective XCD swizzle: 512 blocks -> 64 consecutive per XCD (4 bh)
  const int lin = (int)blockIdx.x + ((int)blockIdx.y << 4);
  const int swz = ((lin & 7) << 6) | (lin >> 3);
  const int qb  = swz & 15;
  const int bh  = swz >> 4;

  const int tid = (int)threadIdx.x;
  const int wv  = tid >> 6;
  const int ln  = tid & 63;
  const int l16 = ln & 15;
  const int lq  = ln >> 4;

  float scale_v;
  {
    union { int i; float f; } u;
    u.i = ((const int*)scale_p)[0];
    float af = fabsf(u.f);
    scale_v = (af >= 1e-6f && af <= 1e6f) ? u.f : (float)u.i;
  }
  const float qmul = LOG2E / scale_v;

  const int q0 = qb * 128;
  const short* Kb = Kp + (size_t)bh * BHSTRIDE;
  const short* Vb = Vp + (size_t)bh * BHSTRIDE;

  __shared__ short Kl[2][4096];
  __shared__ short Vl[2][4096];

  // Q as B-frag: qf[qs][kc][j] = Q[q0+wv*32+qs*16+l16][kc*32+8lq+j]*qmul
  bf16x8 qf[2][2];
#pragma unroll
  for (int qs = 0; qs < 2; ++qs) {
    const float* qrow = Q + ((size_t)bh * NSQ + q0 + wv * 32 + qs * 16 + l16) * ND;
#pragma unroll
    for (int kc = 0; kc < 2; ++kc) {
      const float4* p = (const float4*)(qrow + kc * 32 + lq * 8);
      float4 a = p[0], b = p[1];
      bf16x8 f;
      f[0]=f2bf(a.x*qmul); f[1]=f2bf(a.y*qmul); f[2]=f2bf(a.z*qmul); f[3]=f2bf(a.w*qmul);
      f[4]=f2bf(b.x*qmul); f[5]=f2bf(b.y*qmul); f[6]=f2bf(b.z*qmul); f[7]=f2bf(b.w*qmul);
      qf[qs][kc] = f;
    }
  }

  f32x4 oa[2][4];   // oa[qs][dt][r]: O[q=qs*16+lq*4+r][d=dt*16+l16]
  f32x4 lacc[2];
#pragma unroll
  for (int qs = 0; qs < 2; ++qs) {
#pragma unroll
    for (int dt = 0; dt < 4; ++dt) { f32x4 z = {0.f,0.f,0.f,0.f}; oa[qs][dt] = z; }
    f32x4 z = {0.f,0.f,0.f,0.f}; lacc[qs] = z;
  }

  bf16x8 ones;
#pragma unroll
  for (int j = 0; j < 8; ++j) ones[j] = (short)0x3F80;

  // mask bases: qt(qs) = qb*8 + wv*2 + qs; per-qt stride 32768 ushorts
  const unsigned short* M0 = Mt + (size_t)(qb * 8 + wv * 2) * 32768 + (size_t)ln * 16;
  const unsigned short* M1 = M0 + 32768;

  auto mload = [&](int t, float4* mf0, float4* mf1) {
    const unsigned short* p0 = M0 + (size_t)t * 1024;
    const unsigned short* p1 = M1 + (size_t)t * 1024;
    uint4 a0 = *(const uint4*)p0, b0 = *(const uint4*)(p0 + 8);
    uint4 a1 = *(const uint4*)p1, b1 = *(const uint4*)(p1 + 8);
    const unsigned u0[8] = {a0.x,a0.y,a0.z,a0.w,b0.x,b0.y,b0.z,b0.w};
    const unsigned u1[8] = {a1.x,a1.y,a1.z,a1.w,b1.x,b1.y,b1.z,b1.w};
#pragma unroll
    for (int nt = 0; nt < 4; ++nt) {
      mf0[nt] = float4{u2f(u0[nt*2] << 16), u2f(u0[nt*2] & 0xffff0000u),
                       u2f(u0[nt*2+1] << 16), u2f(u0[nt*2+1] & 0xffff0000u)};
      mf1[nt] = float4{u2f(u1[nt*2] << 16), u2f(u1[nt*2] & 0xffff0000u),
                       u2f(u1[nt*2+1] << 16), u2f(u1[nt*2+1] & 0xffff0000u)};
    }
  };

  auto stage = [&](int t, int buf) {
    const short* ks = Kb + (size_t)t * 4096;
    const short* vs = Vb + (size_t)t * 4096;
#pragma unroll
    for (int i = 0; i < 2; ++i) {
      const int chunk = wv * 2 + i;   // 0..7 x 1KB
      __builtin_amdgcn_global_load_lds((gas_u32*)(ks + chunk * 512 + ln * 8),
                                       (las_u32*)&Kl[buf][chunk * 512], 16, 0, 0);
      __builtin_amdgcn_global_load_lds((gas_u32*)(vs + chunk * 512 + ln * 8),
                                       (las_u32*)&Vl[buf][chunk * 512], 16, 0, 0);
    }
  };

  // softmax (exp2 of QK result, already mask-C-init'd) + pack to A-frags
  auto smpack = [&](f32x4 (&s)[4], bf16x8 (&pa)[2]) {
#pragma unroll
    for (int nt = 0; nt < 4; ++nt) {
      s[nt][0] = exp2_fast(s[nt][0]);
      s[nt][1] = exp2_fast(s[nt][1]);
      s[nt][2] = exp2_fast(s[nt][2]);
      s[nt][3] = exp2_fast(s[nt][3]);
    }
#pragma unroll
    for (int kc = 0; kc < 2; ++kc) {
      union { unsigned u[4]; bf16x8 v; } w;
      w.u[0] = pack_bf2(s[2*kc][0],   s[2*kc][1]);
      w.u[1] = pack_bf2(s[2*kc][2],   s[2*kc][3]);
      w.u[2] = pack_bf2(s[2*kc+1][0], s[2*kc+1][1]);
      w.u[3] = pack_bf2(s[2*kc+1][2], s[2*kc+1][3]);
      pa[kc] = w.v;
    }
  };

  auto tile = [&](int t, int buf, float4 (&mc0)[4], float4 (&mc1)[4],
                  float4 (&mn0)[4], float4 (&mn1)[4]) {
    if (t + 1 < NT) {
      stage(t + 1, buf ^ 1);
      mload(t + 1, mn0, mn1);
    }
    // ---- kf reads + QK for BOTH subtiles (kf dies right after)
    bf16x8 kf[4][2];
#pragma unroll
    for (int nt = 0; nt < 4; ++nt)
#pragma unroll
      for (int kc = 0; kc < 2; ++kc)
        kf[nt][kc] = *(const bf16x8*)&Kl[buf][(nt * 2 + kc) * 512 + ln * 8];

    f32x4 s0[4], s1[4];
    __builtin_amdgcn_s_setprio(1);
#pragma unroll
    for (int nt = 0; nt < 4; ++nt) {
      f32x4 a = *(const f32x4*)&mc0[nt];   // C-init = mask*log2e
      a = __builtin_amdgcn_mfma_f32_16x16x32_bf16(kf[nt][0], qf[0][0], a, 0, 0, 0);
      a = __builtin_amdgcn_mfma_f32_16x16x32_bf16(kf[nt][1], qf[0][1], a, 0, 0, 0);
      s0[nt] = a;
    }
#pragma unroll
    for (int nt = 0; nt < 4; ++nt) {
      f32x4 a = *(const f32x4*)&mc1[nt];
      a = __builtin_amdgcn_mfma_f32_16x16x32_bf16(kf[nt][0], qf[1][0], a, 0, 0, 0);
      a = __builtin_amdgcn_mfma_f32_16x16x32_bf16(kf[nt][1], qf[1][1], a, 0, 0, 0);
      s1[nt] = a;
    }
    __builtin_amdgcn_s_setprio(0);

    // ---- vf reads AFTER QK (spreads LDS pressure out of the tile-top burst)
    bf16x8 vf[4][2];
#pragma unroll
    for (int dt = 0; dt < 4; ++dt)
#pragma unroll
      for (int kc = 0; kc < 2; ++kc)
        vf[dt][kc] = *(const bf16x8*)&Vl[buf][(dt * 2 + kc) * 512 + ln * 8];

    // ---- sm0 -> PV0; sm1 is independent of PV0 -> schedules into its shadow
    bf16x8 pa0[2], pa1[2];
    smpack(s0, pa0);

    __builtin_amdgcn_s_setprio(1);
#pragma unroll
    for (int kc = 0; kc < 2; ++kc) {
#pragma unroll
      for (int dt = 0; dt < 4; ++dt)
        oa[0][dt] = __builtin_amdgcn_mfma_f32_16x16x32_bf16(pa0[kc], vf[dt][kc], oa[0][dt], 0, 0, 0);
      lacc[0] = __builtin_amdgcn_mfma_f32_16x16x32_bf16(pa0[kc], ones, lacc[0], 0, 0, 0);
    }
    __builtin_amdgcn_s_setprio(0);

    smpack(s1, pa1);

    __builtin_amdgcn_s_setprio(1);
#pragma unroll
    for (int kc = 0; kc < 2; ++kc) {
#pragma unroll
      for (int dt = 0; dt < 4; ++dt)
        oa[1][dt] = __builtin_amdgcn_mfma_f32_16x16x32_bf16(pa1[kc], vf[dt][kc], oa[1][dt], 0, 0, 0);
      lacc[1] = __builtin_amdgcn_mfma_f32_16x16x32_bf16(pa1[kc], ones, lacc[1], 0, 0, 0);
    }
    __builtin_amdgcn_s_setprio(0);

    __syncthreads();   // readers of buf done AND stage(t+1) drained
  };

  float4 mA0[4], mA1[4], mB0[4], mB1[4];
  stage(0, 0);
  mload(0, mA0, mA1);
  __syncthreads();

  for (int t = 0; t < NT; t += 2) {
    tile(t,     0, mA0, mA1, mB0, mB1);
    tile(t + 1, 1, mB0, mB1, mA0, mA1);
  }

  // ---- epilogue: normalize by lacc, store fp32
#pragma unroll
  for (int qs = 0; qs < 2; ++qs)
#pragma unroll
    for (int r = 0; r < 4; ++r) {
      const float inv = 1.0f / lacc[qs][r];
      float* orow = O + ((size_t)bh * NSQ + q0 + wv * 32 + qs * 16 + lq * 4 + r) * ND;
#pragma unroll
      for (int dt = 0; dt < 4; ++dt)
        orow[dt * 16 + l16] = oa[qs][dt][r] * inv;
    }
}

extern "C" void kernel_launch(void* const* d_in, const int* in_sizes, int n_in,
                              void* d_out, int out_size, void* d_ws, size_t ws_size,
                              hipStream_t stream) {
  const float* q     = (const float*)d_in[0];
  const float* k     = (const float*)d_in[1];
  const float* v     = (const float*)d_in[2];
  const float* mask  = (const float*)d_in[3];
  const void*  scale = (const void*)d_in[4];
  float* out = (float*)d_out;

  const size_t NELEM = (size_t)NB * NH * NSKV * ND;   // 4,194,304 shorts each
  short* Kpk = (short*)d_ws;
  short* Vpk = Kpk + NELEM;
  unsigned short* Mtl = (unsigned short*)(Vpk + NELEM);   // 8MB bf16

  prep_all<<<dim3(NSKV / 64, NB * NH), 256, 0, stream>>>(k, v, mask, Kpk, Vpk, Mtl);

  dim3 grid(NSQ / 128, NB * NH);
  attn_fwd<<<grid, 256, 0, stream>>>(q, Kpk, Vpk, Mtl, scale, out);
}